// Round 8
// baseline (801.116 us; speedup 1.0000x reference)
//
#include <hip/hip_runtime.h>
#include <hip/hip_bf16.h>
#include <hip/hip_cooperative_groups.h>

#define DD 64
#define CH 512

using f32x4 = __attribute__((ext_vector_type(4))) float;
using bfrag = __attribute__((ext_vector_type(8))) short;   // 8 bf16 = 4 VGPRs
using u32x4 = __attribute__((ext_vector_type(4))) unsigned int;

__device__ __forceinline__ short f2bf(float f) {
    __hip_bfloat16 h = __float2bfloat16(f);
    return *reinterpret_cast<short*>(&h);
}
// native packed f32->bf16 (RNE), one instruction: low16 = a, high16 = b
__device__ __forceinline__ unsigned cvtpk(float a, float b) {
    unsigned r;
    asm("v_cvt_pk_bf16_f32 %0, %1, %2" : "=v"(r) : "v"(a), "v"(b));
    return r;
}
__device__ __forceinline__ float tanh_fast(float x) {
    float e = __expf(-2.f * x);
    return __fdividef(2.f, 1.f + e) - 1.f;
}
template <int CTRL>
__device__ __forceinline__ int dpp_i(int x) {
    return __builtin_amdgcn_update_dpp(0, x, CTRL, 0xF, 0xF, true);
}
template <int CTRL>
__device__ __forceinline__ float dpp_f(float x) {
    return __int_as_float(__builtin_amdgcn_update_dpp(0, __float_as_int(x), CTRL, 0xF, 0xF, true));
}

// ---------------- cooperative build kernel: zero + prep + hist + scan + bin ----------------
__global__ __launch_bounds__(256) void build_kernel(
    const int* __restrict__ idx_i, const int* __restrict__ idx_j,
    const float* __restrict__ w0, const float* __restrict__ w1,
    const float* __restrict__ w2, const float* __restrict__ w3,
    const float* __restrict__ w4, const float* __restrict__ w5,
    unsigned short* __restrict__ wfrag,
    int* __restrict__ counts, int* __restrict__ csum, int* __restrict__ cbase,
    int* __restrict__ cursor, int4* __restrict__ sorted,
    float* __restrict__ out, int n_edges, int n_nodes, int out_elems)
{
    cooperative_groups::grid_group grid = cooperative_groups::this_grid();
    int t = threadIdx.x;
    int gid = blockIdx.x * 256 + t;
    int gsz = gridDim.x * 256;
    __shared__ int s[256];

    // ---- phase A: zero out + counts, prep weight fragments
    for (int i = gid; i < (out_elems >> 2); i += gsz)
        ((float4*)out)[i] = make_float4(0.f, 0.f, 0.f, 0.f);
    for (int i = gid; i < n_nodes; i += gsz) counts[i] = 0;
    {
        const float* W[6] = {w0, w1, w2, w3, w4, w5};
        for (int i = gid; i < 6 * 4096; i += gsz) {
            int l = i >> 12, r = i & 4095;
            int j = r & 7, lane = (r >> 3) & 63, ks = (r >> 9) & 1, dt = r >> 10;
            int k = ks * 32 + (lane >> 4) * 8 + j;
            int d = dt * 16 + (lane & 15);
            wfrag[i] = (unsigned short)f2bf(W[l][k * DD + d]);
        }
    }
    __threadfence();
    grid.sync();

    // ---- phase B: histogram
    for (int e = gid; e < n_edges; e += gsz) atomicAdd(&counts[idx_i[e]], 1);
    __threadfence();
    grid.sync();

    int nch = (n_nodes + CH - 1) / CH;   // <= 256 required (100000/512 = 196)

    // ---- phase C: per-chunk sums
    for (int c = blockIdx.x; c < nch; c += gridDim.x) {
        int base = c * CH + t * 2;
        int v0 = (base < n_nodes) ? counts[base] : 0;
        int v1 = (base + 1 < n_nodes) ? counts[base + 1] : 0;
        s[t] = v0 + v1; __syncthreads();
        for (int d = 128; d; d >>= 1) { if (t < d) s[t] += s[t + d]; __syncthreads(); }
        if (!t) csum[c] = s[0];
        __syncthreads();
    }
    __threadfence();
    grid.sync();

    // ---- phase D: exclusive scan of chunk sums (block 0)
    if (blockIdx.x == 0) {
        int v = (t < nch) ? csum[t] : 0;
        s[t] = v; __syncthreads();
        for (int d = 1; d < 256; d <<= 1) {
            int x = s[t]; if (t >= d) x += s[t - d];
            __syncthreads(); s[t] = x; __syncthreads();
        }
        if (t < nch) cbase[t] = s[t] - v;
    }
    __threadfence();
    grid.sync();

    // ---- phase E: per-chunk exclusive scan -> cursor
    for (int c = blockIdx.x; c < nch; c += gridDim.x) {
        int base = c * CH + t * 2;
        int v0 = (base < n_nodes) ? counts[base] : 0;
        int v1 = (base + 1 < n_nodes) ? counts[base + 1] : 0;
        int sv = v0 + v1;
        s[t] = sv; __syncthreads();
        for (int d = 1; d < 256; d <<= 1) {
            int x = s[t]; if (t >= d) x += s[t - d];
            __syncthreads(); s[t] = x; __syncthreads();
        }
        int excl = s[t] - sv + cbase[c];
        if (base < n_nodes) cursor[base] = excl;
        if (base + 1 < n_nodes) cursor[base + 1] = excl + v0;
        __syncthreads();
    }
    __threadfence();
    grid.sync();

    // ---- phase F: bin edges into sorted order
    for (int e = gid; e < n_edges; e += gsz) {
        int ni = idx_i[e];
        int pos = atomicAdd(&cursor[ni], 1);
        sorted[pos] = make_int4(ni, idx_j[e], e, 0);
    }
}

// one MFMA layer: acc[dt] = bias + W_layer^T-frags * B
__device__ __forceinline__ void mfma_layer(const unsigned short* __restrict__ s_w, int layer,
                                           int lane, const float* __restrict__ s_bias, int g,
                                           bfrag B0, bfrag B1, f32x4 acc[4])
{
#pragma unroll
    for (int dt = 0; dt < 4; ++dt) {
        f32x4 a = *(const f32x4*)&s_bias[dt * 16 + g * 4];
        bfrag A0 = *(const bfrag*)&s_w[(layer * 8 + dt * 2 + 0) * 512 + lane * 8];
        bfrag A1 = *(const bfrag*)&s_w[(layer * 8 + dt * 2 + 1) * 512 + lane * 8];
        a = __builtin_amdgcn_mfma_f32_16x16x32_bf16(A0, B0, a, 0, 0, 0);
        a = __builtin_amdgcn_mfma_f32_16x16x32_bf16(A1, B1, a, 0, 0, 0);
        acc[dt] = a;
    }
}

template <bool ACT>
__device__ __forceinline__ void h_roundtrip(char* H, int swz, int m, int g,
                                            f32x4 acc[4], bfrag B[2])
{
#pragma unroll
    for (int dt = 0; dt < 4; ++dt) {
        float t0, t1, t2, t3;
        if (ACT) {
            t0 = tanh_fast(acc[dt][0]); t1 = tanh_fast(acc[dt][1]);
            t2 = tanh_fast(acc[dt][2]); t3 = tanh_fast(acc[dt][3]);
        } else {
            t0 = acc[dt][0]; t1 = acc[dt][1]; t2 = acc[dt][2]; t3 = acc[dt][3];
        }
        uint2 w;
        w.x = cvtpk(t0, t1);
        w.y = cvtpk(t2, t3);
        *(uint2*)(H + ((m * 128 + dt * 32 + g * 8) ^ swz)) = w;
    }
#pragma unroll
    for (int ks = 0; ks < 2; ++ks)
        B[ks] = *(const bfrag*)(H + ((m * 128 + ks * 64 + g * 16) ^ swz));
}

// ---------------- node MLP: pp1 = tanh(p1@w1+b1)@w2+b2, output bf16 [N][64]
__global__ __launch_bounds__(256) void node_mfma_kernel(
    const float* __restrict__ p1,
    const unsigned short* __restrict__ wfrag,
    const float* __restrict__ b1, const float* __restrict__ b2,
    unsigned short* __restrict__ pp1, int n_rows)
{
    __shared__ __align__(16) unsigned short s_w[2 * 4096];
    __shared__ __align__(16) float s_b[2][DD];
    __shared__ __align__(16) unsigned short s_h[4][1024];

    int tid = threadIdx.x;
    {
        const u32x4* src = (const u32x4*)wfrag;
        u32x4* dst = (u32x4*)s_w;
        for (int i = tid; i < 2 * 4096 / 8; i += 256) dst[i] = src[i];
    }
    if (tid < DD) { s_b[0][tid] = b1[tid]; s_b[1][tid] = b2[tid]; }
    __syncthreads();

    int wave = tid >> 6, lane = tid & 63;
    int g = lane >> 4, m = lane & 15;
    char* H = (char*)s_h[wave];
    int swz = (m & 7) << 4;

    int gw = blockIdx.x * 4 + wave;
    int nw = gridDim.x * 4;
    int ntiles = (n_rows + 15) >> 4;

    for (int t = gw; t < ntiles; t += nw) {
        int row = t * 16 + m;
        int rc = min(row, n_rows - 1);
        bfrag B[2];
#pragma unroll
        for (int ks = 0; ks < 2; ++ks) {
            int f0 = ks * 32 + g * 8;
            f32x4 x0 = *(const f32x4*)(p1 + (size_t)rc * DD + f0);
            f32x4 x1 = *(const f32x4*)(p1 + (size_t)rc * DD + f0 + 4);
            u32x4 r;
            r[0] = cvtpk(x0[0], x0[1]);
            r[1] = cvtpk(x0[2], x0[3]);
            r[2] = cvtpk(x1[0], x1[1]);
            r[3] = cvtpk(x1[2], x1[3]);
            B[ks] = *reinterpret_cast<bfrag*>(&r);
        }
        f32x4 acc[4];
        mfma_layer(s_w, 0, lane, s_b[0], g, B[0], B[1], acc);
        h_roundtrip<true>(H, swz, m, g, acc, B);
        mfma_layer(s_w, 1, lane, s_b[1], g, B[0], B[1], acc);
        if (row < n_rows) {
#pragma unroll
            for (int dt = 0; dt < 4; ++dt) {
                unsigned int* dst = (unsigned int*)((char*)pp1 + (size_t)row * 128 + dt * 32 + g * 8);
                dst[0] = cvtpk(acc[dt][0], acc[dt][1]);
                dst[1] = cvtpk(acc[dt][2], acc[dt][3]);
            }
        }
    }
}

// ---------------- fused edge pipeline over SORTED edges ----------------
struct Gath {
    u32x4 piA, piB, pjA, pjB;      // pp1[ni], pp1[nj] rows (bf16 packed)
    f32x4 b0, b1, b2, b3;          // basis row
};

__device__ __forceinline__ int4 load_rec(const int4* __restrict__ sorted, int t, int m, int n_edges) {
    int gm = t * 16 + m;
    return sorted[min(gm, n_edges - 1)];
}

__device__ __forceinline__ Gath issue_gather(const int4& rec,
                                             const unsigned short* __restrict__ pp1,
                                             const float* __restrict__ basis, int g)
{
    Gath G;
    const unsigned* pi_p = (const unsigned*)(pp1 + (size_t)rec.x * DD);
    const unsigned* pj_p = (const unsigned*)(pp1 + (size_t)rec.y * DD);
    const float* bs = basis + (size_t)rec.z * DD;
    G.piA = *(const u32x4*)(pi_p + g * 4);
    G.piB = *(const u32x4*)(pi_p + 16 + g * 4);
    G.pjA = *(const u32x4*)(pj_p + g * 4);
    G.pjB = *(const u32x4*)(pj_p + 16 + g * 4);
    G.b0 = *(const f32x4*)(bs + g * 8);
    G.b1 = *(const f32x4*)(bs + g * 8 + 4);
    G.b2 = *(const f32x4*)(bs + 32 + g * 8);
    G.b3 = *(const f32x4*)(bs + 32 + g * 8 + 4);
    return G;
}

__device__ __forceinline__ void build_B(const Gath& G, bfrag B[2])
{
    float bf[16];
    *(f32x4*)&bf[0] = G.b0; *(f32x4*)&bf[4] = G.b1;
    *(f32x4*)&bf[8] = G.b2; *(f32x4*)&bf[12] = G.b3;
    u32x4 pi[2] = {G.piA, G.piB};
    u32x4 pj[2] = {G.pjA, G.pjB};
#pragma unroll
    for (int ks = 0; ks < 2; ++ks) {
        u32x4 r;
#pragma unroll
        for (int w = 0; w < 4; ++w) {
            unsigned upi = pi[ks][w], upj = pj[ks][w];
            float lo = __uint_as_float(upi << 16) + bf[ks * 8 + 2 * w]
                     + __uint_as_float(upj << 16);
            float hi = __uint_as_float(upi & 0xFFFF0000u) + bf[ks * 8 + 2 * w + 1]
                     + __uint_as_float(upj & 0xFFFF0000u);
            r[w] = cvtpk(lo, hi);
        }
        B[ks] = *reinterpret_cast<bfrag*>(&r);
    }
}

// 256 threads, no min-wave clamp: VGPR ~160 (no spills), LDS 41984 -> 3 blocks/CU.
__global__ __launch_bounds__(256) void edge_sorted_kernel(
    const int4* __restrict__ sorted,
    const unsigned short* __restrict__ pp1,
    const float* __restrict__ basis,
    const unsigned short* __restrict__ wfrag,   // layers 2..5 = pi_w1, pi_w2, ii_w1, ii_w2
    const float* __restrict__ pi_b1, const float* __restrict__ pi_b2,
    const float* __restrict__ ii_b1, const float* __restrict__ ii_b2,
    float* __restrict__ out, int n_edges, int ntiles)
{
    __shared__ __align__(16) unsigned short s_w[4 * 4096];   // 32 KB frag-order weights
    __shared__ __align__(16) float s_b[4][DD];               // 1 KB
    __shared__ __align__(16) unsigned short s_h[4][1024];    // 8 KB per-wave H

    int tid = threadIdx.x;
    {
        const u32x4* src = (const u32x4*)(wfrag + 2 * 4096);
        u32x4* dst = (u32x4*)s_w;
        for (int i = tid; i < 4 * 4096 / 8; i += 256) dst[i] = src[i];
    }
    if (tid < DD) {
        s_b[0][tid] = pi_b1[tid]; s_b[1][tid] = pi_b2[tid];
        s_b[2][tid] = ii_b1[tid]; s_b[3][tid] = ii_b2[tid];
    }
    __syncthreads();

    int wave = tid >> 6, lane = tid & 63;
    int g = lane >> 4, m = lane & 15;
    char* H = (char*)s_h[wave];
    int swz = (m & 7) << 4;

    int nwaves = gridDim.x * 4;
    int w = blockIdx.x * 4 + wave;
    int tpw = (ntiles + nwaves - 1) / nwaves;
    int t0 = w * tpw;
    int t1 = min(t0 + tpw, ntiles);
    if (t0 >= t1) return;

    int id_before = (t0 > 0) ? sorted[t0 * 16 - 1].x : -2;

    int cur = -9;                 // open carried node id (wave-uniform), -9 = none
    float carry[16];
#pragma unroll
    for (int i = 0; i < 16; ++i) carry[i] = 0.f;

    int4 rec_c = load_rec(sorted, t0, m, n_edges);
    int4 rec_n = load_rec(sorted, t0 + 1, m, n_edges);
    Gath gc = issue_gather(rec_c, pp1, basis, g);   // tile t0's data

    for (int t = t0; t < t1; ++t) {
        int ne = (t + 1) * 16;
        int nf_raw = __shfl(rec_n.x, 0);
        int next_first = (ne < n_edges) ? nf_raw : -3;

        int gm = t * 16 + m;
        int idv = (gm < n_edges) ? rec_c.x : -1;

        // consume gc into B, then immediately reuse gc for tile t+1's gather
        bfrag B[2];
        build_B(gc, B);
        int4 rec_n2 = load_rec(sorted, t + 2, m, n_edges);
        if (t + 1 < t1) gc = issue_gather(rec_n, pp1, basis, g);

        // ---- 4-layer MLP chain
        f32x4 acc[4];
        mfma_layer(s_w, 0, lane, s_b[0], g, B[0], B[1], acc);
        h_roundtrip<true>(H, swz, m, g, acc, B);
        mfma_layer(s_w, 1, lane, s_b[1], g, B[0], B[1], acc);
        h_roundtrip<false>(H, swz, m, g, acc, B);
        mfma_layer(s_w, 2, lane, s_b[2], g, B[0], B[1], acc);
        h_roundtrip<true>(H, swz, m, g, acc, B);
        mfma_layer(s_w, 3, lane, s_b[3], g, B[0], B[1], acc);

        float v[16];
#pragma unroll
        for (int i = 0; i < 16; ++i) v[i] = acc[i >> 2][i & 3];

        // ---- segmented inclusive scan along m (DPP row_shr, ids nondecreasing)
        {
            int idS; float cm;
            idS = dpp_i<0x111>(idv); cm = ((m >= 1) && (idS == idv)) ? 1.f : 0.f;
#pragma unroll
            for (int i = 0; i < 16; ++i) { float sh = dpp_f<0x111>(v[i]); v[i] = fmaf(sh, cm, v[i]); }
            idS = dpp_i<0x112>(idv); cm = ((m >= 2) && (idS == idv)) ? 1.f : 0.f;
#pragma unroll
            for (int i = 0; i < 16; ++i) { float sh = dpp_f<0x112>(v[i]); v[i] = fmaf(sh, cm, v[i]); }
            idS = dpp_i<0x114>(idv); cm = ((m >= 4) && (idS == idv)) ? 1.f : 0.f;
#pragma unroll
            for (int i = 0; i < 16; ++i) { float sh = dpp_f<0x114>(v[i]); v[i] = fmaf(sh, cm, v[i]); }
            idS = dpp_i<0x118>(idv); cm = ((m >= 8) && (idS == idv)) ? 1.f : 0.f;
#pragma unroll
            for (int i = 0; i < 16; ++i) { float sh = dpp_f<0x118>(v[i]); v[i] = fmaf(sh, cm, v[i]); }
        }

        // ---- segment boundaries (lane m=15 handled via next_first)
        int id_next = dpp_i<0x101>(idv);            // row_shl:1 -> lane m gets lane m+1
        bool last = (m == 15);
        bool closes = last ? (idv != next_first) : (idv != id_next);

        if (closes && idv == cur) {
#pragma unroll
            for (int i = 0; i < 16; ++i) v[i] += carry[i];
        }
        if (closes && idv >= 0) {
            size_t ob = (size_t)idv * DD;
            if (idv > id_before) {
                // all edges of idv lie in this wave's range -> exclusive, plain store
#pragma unroll
                for (int dt = 0; dt < 4; ++dt) {
                    f32x4 sv = {v[dt * 4 + 0], v[dt * 4 + 1], v[dt * 4 + 2], v[dt * 4 + 3]};
                    *(f32x4*)&out[ob + (size_t)(dt * 16 + g * 4)] = sv;
                }
            } else {
                // idv == id_before: shared with earlier wave -> atomic
#pragma unroll
                for (int i = 0; i < 16; ++i)
                    atomicAdd(&out[ob + (size_t)((i >> 2) * 16 + g * 4 + (i & 3))], v[i]);
            }
        }

        // ---- carry update (registers only)
        int id15 = __shfl(idv, 15);
        bool cont = (id15 == next_first);
        bool cont_carry = (id15 == cur);
        if (cont) {
#pragma unroll
            for (int i = 0; i < 16; ++i) {
                float s15 = __shfl(v[i], lane | 15);   // row-local lane 15: last-segment sum
                carry[i] = s15 + (cont_carry ? carry[i] : 0.f);
            }
        }
        cur = cont ? id15 : -9;

        rec_c = rec_n; rec_n = rec_n2;
    }

    // flush open carry (node continues into next wave's range -> atomic)
    if (cur >= 0 && m == 0) {
#pragma unroll
        for (int i = 0; i < 16; ++i)
            atomicAdd(&out[(size_t)cur * DD + (size_t)((i >> 2) * 16 + g * 4 + (i & 3))], carry[i]);
    }
}

extern "C" void kernel_launch(void* const* d_in, const int* in_sizes, int n_in,
                              void* d_out, int out_size, void* d_ws, size_t ws_size,
                              hipStream_t stream) {
    const int*   idx_i = (const int*)d_in[0];
    const int*   idx_j = (const int*)d_in[1];
    const float* p1    = (const float*)d_in[2];
    const float* basis = (const float*)d_in[3];
    const float* pp_w1 = (const float*)d_in[4];
    const float* pp_w2 = (const float*)d_in[5];
    const float* pi_w1 = (const float*)d_in[6];
    const float* pi_w2 = (const float*)d_in[7];
    const float* ii_w1 = (const float*)d_in[8];
    const float* ii_w2 = (const float*)d_in[9];
    const float* pp_b1 = (const float*)d_in[10];
    const float* pp_b2 = (const float*)d_in[11];
    const float* pi_b1 = (const float*)d_in[12];
    const float* pi_b2 = (const float*)d_in[13];
    const float* ii_b1 = (const float*)d_in[14];
    const float* ii_b2 = (const float*)d_in[15];

    int n_edges = in_sizes[0];
    int n_nodes = in_sizes[2] / DD;
    int ntiles  = (n_edges + 15) / 16;
    int out_elems = out_size;

    size_t off = 0;
    auto take = [&](size_t b) { size_t o = off; off += (b + 255) & ~(size_t)255; return o; };
    size_t o_wfrag  = take(6 * 4096 * 2);
    size_t o_pp1    = take((size_t)n_nodes * DD * 2);
    size_t o_counts = take((size_t)n_nodes * 4);
    size_t o_csum   = take(1024 * 4);
    size_t o_cbase  = take(1024 * 4);
    size_t o_cursor = take((size_t)n_nodes * 4);
    size_t o_sorted = take((size_t)ntiles * 16 * 16);
    (void)off;

    char* ws = (char*)d_ws;
    unsigned short* wfrag  = (unsigned short*)(ws + o_wfrag);
    unsigned short* pp1    = (unsigned short*)(ws + o_pp1);
    int*            counts = (int*)(ws + o_counts);
    int*            csum   = (int*)(ws + o_csum);
    int*            cbase  = (int*)(ws + o_cbase);
    int*            cursor = (int*)(ws + o_cursor);
    int4*           sorted = (int4*)(ws + o_sorted);
    float* out = (float*)d_out;

    // cooperative fused build: zero(out,counts) + prep + hist + scan + bin
    {
        void* params[] = {
            (void*)&idx_i, (void*)&idx_j,
            (void*)&pp_w1, (void*)&pp_w2, (void*)&pi_w1, (void*)&pi_w2,
            (void*)&ii_w1, (void*)&ii_w2,
            (void*)&wfrag,
            (void*)&counts, (void*)&csum, (void*)&cbase,
            (void*)&cursor, (void*)&sorted,
            (void*)&out, (void*)&n_edges, (void*)&n_nodes, (void*)&out_elems
        };
        hipLaunchCooperativeKernel((const void*)build_kernel, dim3(512), dim3(256),
                                   params, 0, stream);
    }

    node_mfma_kernel<<<512, 256, 0, stream>>>(p1, wfrag, pp_b1, pp_b2, pp1, n_nodes);

    edge_sorted_kernel<<<768, 256, 0, stream>>>(sorted, pp1, basis, wfrag,
                                                pi_b1, pi_b2, ii_b1, ii_b2,
                                                out, n_edges, ntiles);
}

// Round 9
// 315.351 us; speedup vs baseline: 2.5404x; 2.5404x over previous
//
#include <hip/hip_runtime.h>
#include <hip/hip_bf16.h>

#define DD 64

using f32x4 = __attribute__((ext_vector_type(4))) float;
using bfrag = __attribute__((ext_vector_type(8))) short;   // 8 bf16 = 4 VGPRs
using u32x4 = __attribute__((ext_vector_type(4))) unsigned int;

__device__ __forceinline__ short f2bf(float f) {
    __hip_bfloat16 h = __float2bfloat16(f);
    return *reinterpret_cast<short*>(&h);
}
// native packed f32->bf16 (RNE), one instruction: low16 = a, high16 = b
__device__ __forceinline__ unsigned cvtpk(float a, float b) {
    unsigned r;
    asm("v_cvt_pk_bf16_f32 %0, %1, %2" : "=v"(r) : "v"(a), "v"(b));
    return r;
}
__device__ __forceinline__ float tanh_fast(float x) {
    float e = __expf(-2.f * x);
    return __fdividef(2.f, 1.f + e) - 1.f;
}
template <int CTRL>
__device__ __forceinline__ int dpp_i(int x) {
    return __builtin_amdgcn_update_dpp(0, x, CTRL, 0xF, 0xF, true);
}
template <int CTRL>
__device__ __forceinline__ float dpp_f(float x) {
    return __int_as_float(__builtin_amdgcn_update_dpp(0, __float_as_int(x), CTRL, 0xF, 0xF, true));
}

// ---------------- prep: rearrange 6 weight matrices into MFMA A-fragment order (bf16)
__global__ void prep_weights(const float* __restrict__ w0, const float* __restrict__ w1,
                             const float* __restrict__ w2, const float* __restrict__ w3,
                             const float* __restrict__ w4, const float* __restrict__ w5,
                             unsigned short* __restrict__ wfrag)
{
    int t = blockIdx.x * blockDim.x + threadIdx.x;
    if (t >= 6 * 4096) return;
    int l = t >> 12, r = t & 4095;
    int j = r & 7, lane = (r >> 3) & 63, ks = (r >> 9) & 1, dt = r >> 10;
    int k = ks * 32 + (lane >> 4) * 8 + j;
    int d = dt * 16 + (lane & 15);
    const float* W[6] = {w0, w1, w2, w3, w4, w5};
    wfrag[t] = (unsigned short)f2bf(W[l][k * DD + d]);
}

// one MFMA layer: acc[dt] = bias + W_layer^T-frags * B
__device__ __forceinline__ void mfma_layer(const unsigned short* __restrict__ s_w, int layer,
                                           int lane, const float* __restrict__ s_bias, int g,
                                           bfrag B0, bfrag B1, f32x4 acc[4])
{
#pragma unroll
    for (int dt = 0; dt < 4; ++dt) {
        f32x4 a = *(const f32x4*)&s_bias[dt * 16 + g * 4];
        bfrag A0 = *(const bfrag*)&s_w[(layer * 8 + dt * 2 + 0) * 512 + lane * 8];
        bfrag A1 = *(const bfrag*)&s_w[(layer * 8 + dt * 2 + 1) * 512 + lane * 8];
        a = __builtin_amdgcn_mfma_f32_16x16x32_bf16(A0, B0, a, 0, 0, 0);
        a = __builtin_amdgcn_mfma_f32_16x16x32_bf16(A1, B1, a, 0, 0, 0);
        acc[dt] = a;
    }
}

template <bool ACT>
__device__ __forceinline__ void h_roundtrip(char* H, int swz, int m, int g,
                                            f32x4 acc[4], bfrag B[2])
{
#pragma unroll
    for (int dt = 0; dt < 4; ++dt) {
        float t0, t1, t2, t3;
        if (ACT) {
            t0 = tanh_fast(acc[dt][0]); t1 = tanh_fast(acc[dt][1]);
            t2 = tanh_fast(acc[dt][2]); t3 = tanh_fast(acc[dt][3]);
        } else {
            t0 = acc[dt][0]; t1 = acc[dt][1]; t2 = acc[dt][2]; t3 = acc[dt][3];
        }
        uint2 w;
        w.x = cvtpk(t0, t1);
        w.y = cvtpk(t2, t3);
        *(uint2*)(H + ((m * 128 + dt * 32 + g * 8) ^ swz)) = w;
    }
#pragma unroll
    for (int ks = 0; ks < 2; ++ks)
        B[ks] = *(const bfrag*)(H + ((m * 128 + ks * 64 + g * 16) ^ swz));
}

// ---------------- node MLP: pp1 = tanh(p1@w1+b1)@w2+b2, output bf16 [N][64]
__global__ __launch_bounds__(256) void node_mfma_kernel(
    const float* __restrict__ p1,
    const unsigned short* __restrict__ wfrag,
    const float* __restrict__ b1, const float* __restrict__ b2,
    unsigned short* __restrict__ pp1, int n_rows)
{
    __shared__ __align__(16) unsigned short s_w[2 * 4096];
    __shared__ __align__(16) float s_b[2][DD];
    __shared__ __align__(16) unsigned short s_h[4][1024];

    int tid = threadIdx.x;
    {
        const u32x4* src = (const u32x4*)wfrag;
        u32x4* dst = (u32x4*)s_w;
        for (int i = tid; i < 2 * 4096 / 8; i += 256) dst[i] = src[i];
    }
    if (tid < DD) { s_b[0][tid] = b1[tid]; s_b[1][tid] = b2[tid]; }
    __syncthreads();

    int wave = tid >> 6, lane = tid & 63;
    int g = lane >> 4, m = lane & 15;
    char* H = (char*)s_h[wave];
    int swz = (m & 7) << 4;

    int gw = blockIdx.x * 4 + wave;
    int nw = gridDim.x * 4;
    int ntiles = (n_rows + 15) >> 4;

    for (int t = gw; t < ntiles; t += nw) {
        int row = t * 16 + m;
        int rc = min(row, n_rows - 1);
        bfrag B[2];
#pragma unroll
        for (int ks = 0; ks < 2; ++ks) {
            int f0 = ks * 32 + g * 8;
            f32x4 x0 = *(const f32x4*)(p1 + (size_t)rc * DD + f0);
            f32x4 x1 = *(const f32x4*)(p1 + (size_t)rc * DD + f0 + 4);
            u32x4 r;
            r[0] = cvtpk(x0[0], x0[1]);
            r[1] = cvtpk(x0[2], x0[3]);
            r[2] = cvtpk(x1[0], x1[1]);
            r[3] = cvtpk(x1[2], x1[3]);
            B[ks] = *reinterpret_cast<bfrag*>(&r);
        }
        f32x4 acc[4];
        mfma_layer(s_w, 0, lane, s_b[0], g, B[0], B[1], acc);
        h_roundtrip<true>(H, swz, m, g, acc, B);
        mfma_layer(s_w, 1, lane, s_b[1], g, B[0], B[1], acc);
        if (row < n_rows) {
#pragma unroll
            for (int dt = 0; dt < 4; ++dt) {
                unsigned int* dst = (unsigned int*)((char*)pp1 + (size_t)row * 128 + dt * 32 + g * 8);
                dst[0] = cvtpk(acc[dt][0], acc[dt][1]);
                dst[1] = cvtpk(acc[dt][2], acc[dt][3]);
            }
        }
    }
}

// ---------------- CSR build: histogram -> scan -> bin ----------------
__global__ void hist_kernel(const int* __restrict__ idx_i, int* __restrict__ counts, int n) {
    int base = (blockIdx.x * 256 + threadIdx.x) * 4;
    if (base + 3 < n) {
        int4 v = *(const int4*)(idx_i + base);
        atomicAdd(&counts[v.x], 1); atomicAdd(&counts[v.y], 1);
        atomicAdd(&counts[v.z], 1); atomicAdd(&counts[v.w], 1);
    } else {
        for (int e = base; e < n; ++e) atomicAdd(&counts[idx_i[e]], 1);
    }
}

__global__ void chunk_reduce(const int* __restrict__ counts, int* __restrict__ csum, int n) {
    __shared__ int red[256];
    int b = blockIdx.x, t = threadIdx.x;
    int base = b * 1024 + t * 4, s = 0;
#pragma unroll
    for (int j = 0; j < 4; ++j) { int i = base + j; s += (i < n) ? counts[i] : 0; }
    red[t] = s; __syncthreads();
    for (int off = 128; off; off >>= 1) { if (t < off) red[t] += red[t + off]; __syncthreads(); }
    if (!t) csum[b] = red[0];
}

// parallel single-block exclusive scan of chunk sums (nchunks <= 256)
__global__ void scan_tops(const int* __restrict__ csum, int* __restrict__ cbase, int nchunks) {
    __shared__ int s[256];
    int t = threadIdx.x;
    int v = (t < nchunks) ? csum[t] : 0;
    s[t] = v; __syncthreads();
    for (int d = 1; d < 256; d <<= 1) {
        int x = s[t];
        if (t >= d) x += s[t - d];
        __syncthreads();
        s[t] = x;
        __syncthreads();
    }
    if (t < nchunks) cbase[t] = s[t] - v;
}

__global__ void chunk_scan(const int* __restrict__ counts, const int* __restrict__ cbase,
                           int* __restrict__ cursor, int n) {
    __shared__ int sums[256];
    int b = blockIdx.x, t = threadIdx.x;
    int base = b * 1024 + t * 4;
    int v[4], s = 0;
#pragma unroll
    for (int j = 0; j < 4; ++j) { v[j] = (base + j < n) ? counts[base + j] : 0; s += v[j]; }
    sums[t] = s; __syncthreads();
    for (int d = 1; d < 256; d <<= 1) {
        int x = sums[t];
        if (t >= d) x += sums[t - d];
        __syncthreads();
        sums[t] = x;
        __syncthreads();
    }
    int excl = sums[t] - s + cbase[b];
#pragma unroll
    for (int j = 0; j < 4; ++j) {
        if (base + j < n) cursor[base + j] = excl;
        excl += v[j];
    }
}

__global__ void bin_kernel(const int* __restrict__ idx_i, const int* __restrict__ idx_j,
                           int* __restrict__ cursor, int4* __restrict__ sorted, int n) {
    int base = (blockIdx.x * 256 + threadIdx.x) * 4;
    if (base + 3 < n) {
        int4 vi = *(const int4*)(idx_i + base);
        int4 vj = *(const int4*)(idx_j + base);
        int p;
        p = atomicAdd(&cursor[vi.x], 1); sorted[p] = make_int4(vi.x, vj.x, base + 0, 0);
        p = atomicAdd(&cursor[vi.y], 1); sorted[p] = make_int4(vi.y, vj.y, base + 1, 0);
        p = atomicAdd(&cursor[vi.z], 1); sorted[p] = make_int4(vi.z, vj.z, base + 2, 0);
        p = atomicAdd(&cursor[vi.w], 1); sorted[p] = make_int4(vi.w, vj.w, base + 3, 0);
    } else {
        for (int e = base; e < n; ++e) {
            int ni = idx_i[e];
            int p = atomicAdd(&cursor[ni], 1);
            sorted[p] = make_int4(ni, idx_j[e], e, 0);
        }
    }
}

// ---------------- fused edge pipeline over SORTED edges ----------------
struct Gath {
    u32x4 piA, piB, pjA, pjB;      // pp1[ni], pp1[nj] rows (bf16 packed)
    f32x4 b0, b1, b2, b3;          // basis row
};

__device__ __forceinline__ int4 load_rec(const int4* __restrict__ sorted, int t, int m, int n_edges) {
    int gm = t * 16 + m;
    return sorted[min(gm, n_edges - 1)];
}

__device__ __forceinline__ Gath issue_gather(const int4& rec,
                                             const unsigned short* __restrict__ pp1,
                                             const float* __restrict__ basis, int g)
{
    Gath G;
    const unsigned* pi_p = (const unsigned*)(pp1 + (size_t)rec.x * DD);
    const unsigned* pj_p = (const unsigned*)(pp1 + (size_t)rec.y * DD);
    const float* bs = basis + (size_t)rec.z * DD;
    G.piA = *(const u32x4*)(pi_p + g * 4);
    G.piB = *(const u32x4*)(pi_p + 16 + g * 4);
    G.pjA = *(const u32x4*)(pj_p + g * 4);
    G.pjB = *(const u32x4*)(pj_p + 16 + g * 4);
    G.b0 = *(const f32x4*)(bs + g * 8);
    G.b1 = *(const f32x4*)(bs + g * 8 + 4);
    G.b2 = *(const f32x4*)(bs + 32 + g * 8);
    G.b3 = *(const f32x4*)(bs + 32 + g * 8 + 4);
    return G;
}

__device__ __forceinline__ void build_B(const Gath& G, bfrag B[2])
{
    float bf[16];
    *(f32x4*)&bf[0] = G.b0; *(f32x4*)&bf[4] = G.b1;
    *(f32x4*)&bf[8] = G.b2; *(f32x4*)&bf[12] = G.b3;
    u32x4 pi[2] = {G.piA, G.piB};
    u32x4 pj[2] = {G.pjA, G.pjB};
#pragma unroll
    for (int ks = 0; ks < 2; ++ks) {
        u32x4 r;
#pragma unroll
        for (int w = 0; w < 4; ++w) {
            unsigned upi = pi[ks][w], upj = pj[ks][w];
            float lo = __uint_as_float(upi << 16) + bf[ks * 8 + 2 * w]
                     + __uint_as_float(upj << 16);
            float hi = __uint_as_float(upi & 0xFFFF0000u) + bf[ks * 8 + 2 * w + 1]
                     + __uint_as_float(upj & 0xFFFF0000u);
            r[w] = cvtpk(lo, hi);
        }
        B[ks] = *reinterpret_cast<bfrag*>(&r);
    }
}

// 256 threads, no min-wave clamp: VGPR ~150 (no spills), LDS 41984 -> 3 blocks/CU.
__global__ __launch_bounds__(256) void edge_sorted_kernel(
    const int4* __restrict__ sorted,
    const unsigned short* __restrict__ pp1,
    const float* __restrict__ basis,
    const unsigned short* __restrict__ wfrag,   // layers 2..5 = pi_w1, pi_w2, ii_w1, ii_w2
    const float* __restrict__ pi_b1, const float* __restrict__ pi_b2,
    const float* __restrict__ ii_b1, const float* __restrict__ ii_b2,
    float* __restrict__ out, int n_edges, int ntiles)
{
    __shared__ __align__(16) unsigned short s_w[4 * 4096];   // 32 KB frag-order weights
    __shared__ __align__(16) float s_b[4][DD];               // 1 KB
    __shared__ __align__(16) unsigned short s_h[4][1024];    // 8 KB per-wave H

    int tid = threadIdx.x;
    {
        const u32x4* src = (const u32x4*)(wfrag + 2 * 4096);
        u32x4* dst = (u32x4*)s_w;
        for (int i = tid; i < 4 * 4096 / 8; i += 256) dst[i] = src[i];
    }
    if (tid < DD) {
        s_b[0][tid] = pi_b1[tid]; s_b[1][tid] = pi_b2[tid];
        s_b[2][tid] = ii_b1[tid]; s_b[3][tid] = ii_b2[tid];
    }
    __syncthreads();

    int wave = tid >> 6, lane = tid & 63;
    int g = lane >> 4, m = lane & 15;
    char* H = (char*)s_h[wave];
    int swz = (m & 7) << 4;

    int nwaves = gridDim.x * 4;
    int w = blockIdx.x * 4 + wave;
    int tpw = (ntiles + nwaves - 1) / nwaves;
    int t0 = w * tpw;
    int t1 = min(t0 + tpw, ntiles);
    if (t0 >= t1) return;

    int id_before = (t0 > 0) ? sorted[t0 * 16 - 1].x : -2;

    int cur = -9;                 // open carried node id (wave-uniform), -9 = none
    float carry[16];
#pragma unroll
    for (int i = 0; i < 16; ++i) carry[i] = 0.f;

    int4 rec_c = load_rec(sorted, t0, m, n_edges);
    int4 rec_n = load_rec(sorted, t0 + 1, m, n_edges);
    Gath gc = issue_gather(rec_c, pp1, basis, g);   // tile t0's data

    for (int t = t0; t < t1; ++t) {
        int ne = (t + 1) * 16;
        int nf_raw = __shfl(rec_n.x, 0);
        int next_first = (ne < n_edges) ? nf_raw : -3;

        int gm = t * 16 + m;
        int idv = (gm < n_edges) ? rec_c.x : -1;

        // consume gc into B, then immediately reuse gc for tile t+1's gather
        bfrag B[2];
        build_B(gc, B);
        int4 rec_n2 = load_rec(sorted, t + 2, m, n_edges);
        if (t + 1 < t1) gc = issue_gather(rec_n, pp1, basis, g);

        // ---- 4-layer MLP chain
        f32x4 acc[4];
        mfma_layer(s_w, 0, lane, s_b[0], g, B[0], B[1], acc);
        h_roundtrip<true>(H, swz, m, g, acc, B);
        mfma_layer(s_w, 1, lane, s_b[1], g, B[0], B[1], acc);
        h_roundtrip<false>(H, swz, m, g, acc, B);
        mfma_layer(s_w, 2, lane, s_b[2], g, B[0], B[1], acc);
        h_roundtrip<true>(H, swz, m, g, acc, B);
        mfma_layer(s_w, 3, lane, s_b[3], g, B[0], B[1], acc);

        float v[16];
#pragma unroll
        for (int i = 0; i < 16; ++i) v[i] = acc[i >> 2][i & 3];

        // ---- segmented inclusive scan along m (DPP row_shr, ids nondecreasing)
        {
            int idS; float cm;
            idS = dpp_i<0x111>(idv); cm = ((m >= 1) && (idS == idv)) ? 1.f : 0.f;
#pragma unroll
            for (int i = 0; i < 16; ++i) { float sh = dpp_f<0x111>(v[i]); v[i] = fmaf(sh, cm, v[i]); }
            idS = dpp_i<0x112>(idv); cm = ((m >= 2) && (idS == idv)) ? 1.f : 0.f;
#pragma unroll
            for (int i = 0; i < 16; ++i) { float sh = dpp_f<0x112>(v[i]); v[i] = fmaf(sh, cm, v[i]); }
            idS = dpp_i<0x114>(idv); cm = ((m >= 4) && (idS == idv)) ? 1.f : 0.f;
#pragma unroll
            for (int i = 0; i < 16; ++i) { float sh = dpp_f<0x114>(v[i]); v[i] = fmaf(sh, cm, v[i]); }
            idS = dpp_i<0x118>(idv); cm = ((m >= 8) && (idS == idv)) ? 1.f : 0.f;
#pragma unroll
            for (int i = 0; i < 16; ++i) { float sh = dpp_f<0x118>(v[i]); v[i] = fmaf(sh, cm, v[i]); }
        }

        // ---- segment boundaries (lane m=15 handled via next_first)
        int id_next = dpp_i<0x101>(idv);            // row_shl:1 -> lane m gets lane m+1
        bool last = (m == 15);
        bool closes = last ? (idv != next_first) : (idv != id_next);

        if (closes && idv == cur) {
#pragma unroll
            for (int i = 0; i < 16; ++i) v[i] += carry[i];
        }
        if (closes && idv >= 0) {
            size_t ob = (size_t)idv * DD;
            if (idv > id_before) {
                // all edges of idv lie in this wave's range -> exclusive, plain store
#pragma unroll
                for (int dt = 0; dt < 4; ++dt) {
                    f32x4 sv = {v[dt * 4 + 0], v[dt * 4 + 1], v[dt * 4 + 2], v[dt * 4 + 3]};
                    *(f32x4*)&out[ob + (size_t)(dt * 16 + g * 4)] = sv;
                }
            } else {
                // idv == id_before: shared with earlier wave -> atomic
#pragma unroll
                for (int i = 0; i < 16; ++i)
                    atomicAdd(&out[ob + (size_t)((i >> 2) * 16 + g * 4 + (i & 3))], v[i]);
            }
        }

        // ---- carry update (registers only)
        int id15 = __shfl(idv, 15);
        bool cont = (id15 == next_first);
        bool cont_carry = (id15 == cur);
        if (cont) {
#pragma unroll
            for (int i = 0; i < 16; ++i) {
                float s15 = __shfl(v[i], lane | 15);   // row-local lane 15: last-segment sum
                carry[i] = s15 + (cont_carry ? carry[i] : 0.f);
            }
        }
        cur = cont ? id15 : -9;

        rec_c = rec_n; rec_n = rec_n2;
    }

    // flush open carry (node continues into next wave's range -> atomic)
    if (cur >= 0 && m == 0) {
#pragma unroll
        for (int i = 0; i < 16; ++i)
            atomicAdd(&out[(size_t)cur * DD + (size_t)((i >> 2) * 16 + g * 4 + (i & 3))], carry[i]);
    }
}

extern "C" void kernel_launch(void* const* d_in, const int* in_sizes, int n_in,
                              void* d_out, int out_size, void* d_ws, size_t ws_size,
                              hipStream_t stream) {
    const int*   idx_i = (const int*)d_in[0];
    const int*   idx_j = (const int*)d_in[1];
    const float* p1    = (const float*)d_in[2];
    const float* basis = (const float*)d_in[3];
    const float* pp_w1 = (const float*)d_in[4];
    const float* pp_w2 = (const float*)d_in[5];
    const float* pi_w1 = (const float*)d_in[6];
    const float* pi_w2 = (const float*)d_in[7];
    const float* ii_w1 = (const float*)d_in[8];
    const float* ii_w2 = (const float*)d_in[9];
    const float* pp_b1 = (const float*)d_in[10];
    const float* pp_b2 = (const float*)d_in[11];
    const float* pi_b1 = (const float*)d_in[12];
    const float* pi_b2 = (const float*)d_in[13];
    const float* ii_b1 = (const float*)d_in[14];
    const float* ii_b2 = (const float*)d_in[15];

    int n_edges = in_sizes[0];
    int n_nodes = in_sizes[2] / DD;
    int ntiles  = (n_edges + 15) / 16;

    size_t off = 0;
    auto take = [&](size_t b) { size_t o = off; off += (b + 255) & ~(size_t)255; return o; };
    size_t o_wfrag  = take(6 * 4096 * 2);
    size_t o_pp1    = take((size_t)n_nodes * DD * 2);
    size_t o_counts = take((size_t)n_nodes * 4);
    size_t o_csum   = take(1024 * 4);
    size_t o_cbase  = take(1024 * 4);
    size_t o_cursor = take((size_t)n_nodes * 4);
    size_t o_sorted = take((size_t)ntiles * 16 * 16);
    (void)off;

    char* ws = (char*)d_ws;
    unsigned short* wfrag  = (unsigned short*)(ws + o_wfrag);
    unsigned short* pp1    = (unsigned short*)(ws + o_pp1);
    int*            counts = (int*)(ws + o_counts);
    int*            csum   = (int*)(ws + o_csum);
    int*            cbase  = (int*)(ws + o_cbase);
    int*            cursor = (int*)(ws + o_cursor);
    int4*           sorted = (int4*)(ws + o_sorted);
    float* out = (float*)d_out;

    hipMemsetAsync(d_out, 0, (size_t)out_size * sizeof(float), stream);
    hipMemsetAsync(counts, 0, (size_t)n_nodes * 4, stream);

    prep_weights<<<96, 256, 0, stream>>>(pp_w1, pp_w2, pi_w1, pi_w2, ii_w1, ii_w2, wfrag);
    node_mfma_kernel<<<512, 256, 0, stream>>>(p1, wfrag, pp_b1, pp_b2, pp1, n_nodes);

    int eg4 = (n_edges / 4 + 255) / 256 + 1;
    int nch = (n_nodes + 1023) / 1024;
    hist_kernel<<<eg4, 256, 0, stream>>>(idx_i, counts, n_edges);
    chunk_reduce<<<nch, 256, 0, stream>>>(counts, csum, n_nodes);
    scan_tops<<<1, 256, 0, stream>>>(csum, cbase, nch);
    chunk_scan<<<nch, 256, 0, stream>>>(counts, cbase, cursor, n_nodes);
    bin_kernel<<<eg4, 256, 0, stream>>>(idx_i, idx_j, cursor, sorted, n_edges);

    edge_sorted_kernel<<<768, 256, 0, stream>>>(sorted, pp1, basis, wfrag,
                                                pi_b1, pi_b2, ii_b1, ii_b2,
                                                out, n_edges, ntiles);
}